// Round 1
// baseline (388.599 us; speedup 1.0000x reference)
//
#include <hip/hip_runtime.h>

typedef _Float16 f16;
typedef __attribute__((ext_vector_type(4))) _Float16 f16x4;
typedef __attribute__((ext_vector_type(8))) _Float16 f16x8;
typedef __attribute__((ext_vector_type(4))) float f32x4;

// ---------------------------------------------------------------------------
// Sparsify (2:4 soft-threshold) * scale -> fp16, stored TRANSPOSED: Wt[M][K].
// Groups of 4 are contiguous along the last dim (M) of W[K][M].
// t = 2nd-smallest |w| in the group (== 3rd-largest); out = sign(w)*max(|w|-t,0)*s
// ---------------------------------------------------------------------------
__global__ void sparsify_t_kernel(const float* __restrict__ W,
                                  const float* __restrict__ scale,
                                  f16* __restrict__ Wt, int K, int M) {
    int gpr = M >> 2;                       // groups per row
    int g = blockIdx.x * blockDim.x + threadIdx.x;
    if (g >= K * gpr) return;
    int r = g / gpr;
    int c = g - r * gpr;
    float4 v = *(const float4*)(W + (size_t)r * M + ((size_t)c << 2));
    float s = scale[0];
    float a0 = fabsf(v.x), a1 = fabsf(v.y), a2 = fabsf(v.z), a3 = fabsf(v.w);
    // median network: 2nd smallest of 4
    float lo1 = fminf(a0, a1), hi1 = fmaxf(a0, a1);
    float lo2 = fminf(a2, a3), hi2 = fmaxf(a2, a3);
    float t = fminf(fmaxf(lo1, lo2), fminf(hi1, hi2));
    float o0 = copysignf(fmaxf(a0 - t, 0.f), v.x) * s;
    float o1 = copysignf(fmaxf(a1 - t, 0.f), v.y) * s;
    float o2 = copysignf(fmaxf(a2 - t, 0.f), v.z) * s;
    float o3 = copysignf(fmaxf(a3 - t, 0.f), v.w) * s;
    int m = c << 2;
    Wt[(size_t)(m + 0) * K + r] = (f16)o0;
    Wt[(size_t)(m + 1) * K + r] = (f16)o1;
    Wt[(size_t)(m + 2) * K + r] = (f16)o2;
    Wt[(size_t)(m + 3) * K + r] = (f16)o3;
}

// ---------------------------------------------------------------------------
// C[Nrows][Mcols] = cast_fp16(A[Nrows][K]) @ Bt[Mcols][K]^T  (+ bias[Mcols])
// fp32 accumulation via v_mfma_f32_16x16x32_f16.
// Block = 256 threads = 4 waves; wave tile = 64x64 (4x4 of 16x16 MFMA).
// A layout per lane:  A[m = lane&15][k = quad*8 + j], j=0..7  (16B ds_read)
// B layout per lane:  B[k = quad*8 + j][n = lane&15]          (from Bt rows)
// C/D layout:         col = lane&15, row = quad*4 + reg       (verified m89)
// ---------------------------------------------------------------------------
template<int BM, int BN, int WM, int WN, bool A_F32, bool OUT_F16>
__global__ __launch_bounds__(256)
void gemm_bt_kernel(const void* __restrict__ A_, const f16* __restrict__ Bt,
                    const float* __restrict__ bias, void* __restrict__ Out,
                    int K, int Mcols) {
    static_assert(BM == WM * 64 && BN == WN * 64, "wave tiling mismatch");
    constexpr int BK  = 32;
    constexpr int LDK = BK + 8;   // +16B pad: keeps 16B alignment, breaks bank aliasing
    __shared__ f16 As[BM][LDK];
    __shared__ f16 Bs[BN][LDK];

    const int tid  = threadIdx.x;
    const int lane = tid & 63;
    const int wv   = tid >> 6;
    const int wm   = wv % WM;
    const int wn   = wv / WM;
    const int row0 = blockIdx.y * BM;
    const int col0 = blockIdx.x * BN;
    const int lr   = lane & 15;
    const int quad = lane >> 4;

    f32x4 acc[4][4] = {};

    for (int k0 = 0; k0 < K; k0 += BK) {
        // ---- stage A tile (convert fp32->fp16 if needed) ----
        if constexpr (A_F32) {
            const float* A = (const float*)A_;
            #pragma unroll
            for (int i = tid; i < BM * 8; i += 256) {
                int r = i >> 3, c4 = (i & 7) << 2;
                float4 v = *(const float4*)(A + (size_t)(row0 + r) * K + k0 + c4);
                f16x4 h;
                h.x = (f16)v.x; h.y = (f16)v.y; h.z = (f16)v.z; h.w = (f16)v.w;
                *(f16x4*)&As[r][c4] = h;
            }
        } else {
            const f16* A = (const f16*)A_;
            #pragma unroll
            for (int i = tid; i < BM * 4; i += 256) {
                int r = i >> 2, c8 = (i & 3) << 3;
                *(f16x8*)&As[r][c8] = *(const f16x8*)(A + (size_t)(row0 + r) * K + k0 + c8);
            }
        }
        // ---- stage B tile (already fp16, already transposed) ----
        #pragma unroll
        for (int i = tid; i < BN * 4; i += 256) {
            int r = i >> 2, c8 = (i & 3) << 3;
            *(f16x8*)&Bs[r][c8] = *(const f16x8*)(Bt + (size_t)(col0 + r) * K + k0 + c8);
        }
        __syncthreads();

        f16x8 afr[4], bfr[4];
        #pragma unroll
        for (int m = 0; m < 4; m++)
            afr[m] = *(const f16x8*)&As[wm * 64 + m * 16 + lr][quad * 8];
        #pragma unroll
        for (int n = 0; n < 4; n++)
            bfr[n] = *(const f16x8*)&Bs[wn * 64 + n * 16 + lr][quad * 8];
        #pragma unroll
        for (int m = 0; m < 4; m++)
            #pragma unroll
            for (int n = 0; n < 4; n++)
                acc[m][n] = __builtin_amdgcn_mfma_f32_16x16x32_f16(
                    afr[m], bfr[n], acc[m][n], 0, 0, 0);
        __syncthreads();
    }

    // ---- epilogue: add bias, store ----
    #pragma unroll
    for (int m = 0; m < 4; m++) {
        int gr0 = row0 + wm * 64 + m * 16 + quad * 4;
        #pragma unroll
        for (int n = 0; n < 4; n++) {
            int gc = col0 + wn * 64 + n * 16 + lr;
            float bv = bias[gc];
            #pragma unroll
            for (int r = 0; r < 4; r++) {
                float v = acc[m][n][r] + bv;
                if constexpr (OUT_F16)
                    ((f16*)Out)[(size_t)(gr0 + r) * Mcols + gc] = (f16)v;
                else
                    ((float*)Out)[(size_t)(gr0 + r) * Mcols + gc] = v;
            }
        }
    }
}

// ---------------------------------------------------------------------------
// launch
// ---------------------------------------------------------------------------
extern "C" void kernel_launch(void* const* d_in, const int* in_sizes, int n_in,
                              void* d_out, int out_size, void* d_ws, size_t ws_size,
                              hipStream_t stream) {
    const float* x  = (const float*)d_in[0];   // [8,2048,2048]
    const float* w1 = (const float*)d_in[1];   // [2048,256]
    const float* w2 = (const float*)d_in[2];   // [256,2048]
    const float* b1 = (const float*)d_in[3];   // [256]
    const float* b2 = (const float*)d_in[4];   // [2048]
    const float* s1 = (const float*)d_in[5];   // [1]
    const float* s2 = (const float*)d_in[6];   // [1]
    float* y = (float*)d_out;                  // [8,2048,2048] fp32

    constexpr int NROWS = 8 * 2048;  // 16384
    constexpr int D = 2048, R = 256;

    char* ws = (char*)d_ws;
    f16* W1t = (f16*)ws;                             // [R][D]  fp16, 1 MiB
    f16* W2t = (f16*)(ws + (size_t)R * D * 2);       // [D][R]  fp16, 1 MiB
    f16* H   = (f16*)(ws + (size_t)R * D * 4);       // [NROWS][R] fp16, 8 MiB

    // sparsify + transpose both weights
    int groups1 = D * (R >> 2);
    hipLaunchKernelGGL(sparsify_t_kernel, dim3((groups1 + 255) / 256), dim3(256),
                       0, stream, w1, s1, W1t, D, R);
    int groups2 = R * (D >> 2);
    hipLaunchKernelGGL(sparsify_t_kernel, dim3((groups2 + 255) / 256), dim3(256),
                       0, stream, w2, s2, W2t, R, D);

    // GEMM1: H[16384][256] = fp16(x) @ W1s  (+bias_in, stored as fp16)
    // BN=256 spans all of R -> x is read exactly once from HBM.
    hipLaunchKernelGGL((gemm_bt_kernel<64, 256, 1, 4, true, true>),
                       dim3(1, NROWS / 64), dim3(256), 0, stream,
                       (const void*)x, W1t, b1, (void*)H, D, R);

    // GEMM2: y[16384][2048] = H @ W2s (+bias_out, fp32 out)
    hipLaunchKernelGGL((gemm_bt_kernel<128, 128, 2, 2, false, false>),
                       dim3(D / 128, NROWS / 128), dim3(256), 0, stream,
                       (const void*)H, W2t, b2, (void*)y, R, D);
}

// Round 2
// 297.667 us; speedup vs baseline: 1.3055x; 1.3055x over previous
//
#include <hip/hip_runtime.h>
#include <stdint.h>
#include <stddef.h>

typedef _Float16 f16;
typedef __attribute__((ext_vector_type(8))) _Float16 f16x8;
typedef __attribute__((ext_vector_type(4))) float f32x4;

#define GPTR(p) ((const __attribute__((address_space(1))) void*)(p))
#define LPTR(p) ((__attribute__((address_space(3))) void*)(p))

// async global->LDS, 16B per lane; LDS dest = wave-uniform base + lane*16
__device__ __forceinline__ void async16(const void* g, void* l) {
    __builtin_amdgcn_global_load_lds(GPTR(g), LPTR(l), 16, 0, 0);
}

// ---------------------------------------------------------------------------
// Sparsify (2:4 soft-threshold along last dim of W[K][M]) * scale -> fp16,
// stored transposed Wt[M][K]. Tiled 64x64 with LDS transpose: coalesced
// global reads AND writes.
// ---------------------------------------------------------------------------
__global__ __launch_bounds__(256) void sparsify_t_tiled(
        const float* __restrict__ W, const float* __restrict__ scale,
        f16* __restrict__ Wt, int K, int M) {
    __shared__ f16 T[64][80];      // [m][r], stride 160B (16B-aligned rows)
    const int r0 = blockIdx.y << 6, m0 = blockIdx.x << 6;
    const float s = scale[0];
    const int t = threadIdx.x;
    const int rr = t >> 2, mb = (t & 3) << 4;
    const float* src = W + (size_t)(r0 + rr) * M + m0 + mb;
    #pragma unroll
    for (int j = 0; j < 4; j++) {
        float4 v = *(const float4*)(src + j * 4);   // one 2:4 group
        float a0 = fabsf(v.x), a1 = fabsf(v.y), a2 = fabsf(v.z), a3 = fabsf(v.w);
        float lo1 = fminf(a0, a1), hi1 = fmaxf(a0, a1);
        float lo2 = fminf(a2, a3), hi2 = fmaxf(a2, a3);
        float th = fminf(fmaxf(lo1, lo2), fminf(hi1, hi2));  // 2nd-smallest
        int m = mb + j * 4;
        T[m + 0][rr] = (f16)(copysignf(fmaxf(a0 - th, 0.f), v.x) * s);
        T[m + 1][rr] = (f16)(copysignf(fmaxf(a1 - th, 0.f), v.y) * s);
        T[m + 2][rr] = (f16)(copysignf(fmaxf(a2 - th, 0.f), v.z) * s);
        T[m + 3][rr] = (f16)(copysignf(fmaxf(a3 - th, 0.f), v.w) * s);
    }
    __syncthreads();
    const int mm = t >> 2, rb = (t & 3) << 4;
    f16* dst = Wt + (size_t)(m0 + mm) * K + r0 + rb;
    *(f16x8*)dst       = *(const f16x8*)&T[mm][rb];
    *(f16x8*)(dst + 8) = *(const f16x8*)&T[mm][rb + 8];
}

// ---------------------------------------------------------------------------
// GEMM1: H[16384][256](f16) = fp16(x[16384][2048]) @ W1t[256][2048]^T + b1
// BM=64 BN=64 BK=64, 4 waves as 2x2 of 32x32 wave-tiles.
// A staged fp32 via global_load_lds (XOR-swizzled chunks), converted RNE at
// fragment read. B staged f16 via global_load_lds (XOR-swizzled).
// Swizzle: 16B chunk c of row r lives at LDS chunk (c&~7)|((c&7)^(r&7)).
// ---------------------------------------------------------------------------
__global__ __launch_bounds__(256, 4) void gemm1_kernel(
        const float* __restrict__ A, const f16* __restrict__ Bt,
        const float* __restrict__ bias, f16* __restrict__ H) {
    constexpr int K = 2048, RN = 256, BK = 64;
    __shared__ float4 Asf[64 * 16];   // 16 KB, swizzled [r][c']
    __shared__ f16x8  Bs[64 * 8];     //  8 KB, swizzled [r][c']

    const int tid  = threadIdx.x;
    const int lane = tid & 63;
    const int wv   = tid >> 6;
    const int wm   = wv & 1, wn = wv >> 1;
    const int lr   = lane & 15, q = lane >> 4;
    const int row0 = blockIdx.y << 6;
    const int col0 = blockIdx.x << 6;

    f32x4 acc[2][2] = {};

    for (int k0 = 0; k0 < K; k0 += BK) {
        // stage A: 16 wave-issues of 64 lanes x 16B; this wave does 4
        #pragma unroll
        for (int j = 0; j < 4; j++) {
            int issue = wv * 4 + j;
            int L = issue * 64 + lane;
            int r = L >> 4, cp = L & 15;
            int c = (cp & 8) | ((cp & 7) ^ (r & 7));       // unswizzle (self-inverse)
            async16(A + (size_t)(row0 + r) * K + k0 + c * 4,
                    (char*)Asf + issue * 1024);
        }
        // stage B: 8 wave-issues; this wave does 2
        #pragma unroll
        for (int j = 0; j < 2; j++) {
            int issue = wv * 2 + j;
            int L = issue * 64 + lane;
            int r = L >> 3, cp = L & 7;
            int c = cp ^ (r & 7);
            async16(Bt + (size_t)(col0 + r) * K + k0 + c * 8,
                    (char*)Bs + issue * 1024);
        }
        __syncthreads();

        #pragma unroll
        for (int ks = 0; ks < 2; ks++) {
            f16x8 af[2], bf[2];
            #pragma unroll
            for (int m = 0; m < 2; m++) {
                int r = wm * 32 + m * 16 + lr;
                int c0p = ks * 8 + (((2 * q) + 0) ^ (r & 7));
                int c1p = ks * 8 + (((2 * q) + 1) ^ (r & 7));
                float4 v0 = Asf[r * 16 + c0p];
                float4 v1 = Asf[r * 16 + c1p];
                f16x8 h;
                h[0] = (f16)v0.x; h[1] = (f16)v0.y; h[2] = (f16)v0.z; h[3] = (f16)v0.w;
                h[4] = (f16)v1.x; h[5] = (f16)v1.y; h[6] = (f16)v1.z; h[7] = (f16)v1.w;
                af[m] = h;
            }
            #pragma unroll
            for (int n = 0; n < 2; n++) {
                int r = wn * 32 + n * 16 + lr;
                int cp = (ks * 4 + q) ^ (r & 7);
                bf[n] = Bs[r * 8 + cp];
            }
            #pragma unroll
            for (int m = 0; m < 2; m++)
                #pragma unroll
                for (int n = 0; n < 2; n++)
                    acc[m][n] = __builtin_amdgcn_mfma_f32_16x16x32_f16(
                        af[m], bf[n], acc[m][n], 0, 0, 0);
        }
        __syncthreads();
    }

    #pragma unroll
    for (int m = 0; m < 2; m++) {
        int gr0 = row0 + wm * 32 + m * 16 + q * 4;
        #pragma unroll
        for (int n = 0; n < 2; n++) {
            int gc = col0 + wn * 32 + n * 16 + lr;
            float bv = bias[gc];
            #pragma unroll
            for (int r = 0; r < 4; r++)
                H[(size_t)(gr0 + r) * RN + gc] = (f16)(acc[m][n][r] + bv);
        }
    }
}

// ---------------------------------------------------------------------------
// GEMM2: y[16384][2048](f32) = H[16384][256](f16) @ W2t[2048][256]^T + b2
// BM=64 BN=128 BK=64 (4 K-iters), 4 waves as 2x2 of 32x64 wave-tiles.
// All staging f16 via global_load_lds, XOR-swizzled.
// ---------------------------------------------------------------------------
__global__ __launch_bounds__(256, 4) void gemm2_kernel(
        const f16* __restrict__ H, const f16* __restrict__ Bt,
        const float* __restrict__ bias, float* __restrict__ Y) {
    constexpr int K = 256, N = 2048, BK = 64;
    __shared__ f16x8 As[64 * 8];    //  8 KB
    __shared__ f16x8 Bs[128 * 8];   // 16 KB

    const int tid  = threadIdx.x;
    const int lane = tid & 63;
    const int wv   = tid >> 6;
    const int wm   = wv & 1, wn = wv >> 1;
    const int lr   = lane & 15, q = lane >> 4;
    const int row0 = blockIdx.y << 6;
    const int col0 = blockIdx.x << 7;

    f32x4 acc[2][4] = {};

    for (int k0 = 0; k0 < K; k0 += BK) {
        #pragma unroll
        for (int j = 0; j < 2; j++) {          // A: 8 issues total
            int issue = wv * 2 + j;
            int L = issue * 64 + lane;
            int r = L >> 3, cp = L & 7;
            int c = cp ^ (r & 7);
            async16(H + (size_t)(row0 + r) * K + k0 + c * 8,
                    (char*)As + issue * 1024);
        }
        #pragma unroll
        for (int j = 0; j < 4; j++) {          // B: 16 issues total
            int issue = wv * 4 + j;
            int L = issue * 64 + lane;
            int r = L >> 3, cp = L & 7;
            int c = cp ^ (r & 7);
            async16(Bt + (size_t)(col0 + r) * K + k0 + c * 8,
                    (char*)Bs + issue * 1024);
        }
        __syncthreads();

        #pragma unroll
        for (int ks = 0; ks < 2; ks++) {
            f16x8 af[2], bf[4];
            #pragma unroll
            for (int m = 0; m < 2; m++) {
                int r = wm * 32 + m * 16 + lr;
                af[m] = As[r * 8 + ((ks * 4 + q) ^ (r & 7))];
            }
            #pragma unroll
            for (int n = 0; n < 4; n++) {
                int r = wn * 64 + n * 16 + lr;
                bf[n] = Bs[r * 8 + ((ks * 4 + q) ^ (r & 7))];
            }
            #pragma unroll
            for (int m = 0; m < 2; m++)
                #pragma unroll
                for (int n = 0; n < 4; n++)
                    acc[m][n] = __builtin_amdgcn_mfma_f32_16x16x32_f16(
                        af[m], bf[n], acc[m][n], 0, 0, 0);
        }
        __syncthreads();
    }

    #pragma unroll
    for (int m = 0; m < 2; m++) {
        int gr0 = row0 + wm * 32 + m * 16 + q * 4;
        #pragma unroll
        for (int n = 0; n < 4; n++) {
            int gc = col0 + wn * 64 + n * 16 + lr;
            float bv = bias[gc];
            #pragma unroll
            for (int r = 0; r < 4; r++)
                Y[(size_t)(gr0 + r) * N + gc] = acc[m][n][r] + bv;
        }
    }
}

// ---------------------------------------------------------------------------
// launch
// ---------------------------------------------------------------------------
extern "C" void kernel_launch(void* const* d_in, const int* in_sizes, int n_in,
                              void* d_out, int out_size, void* d_ws, size_t ws_size,
                              hipStream_t stream) {
    const float* x  = (const float*)d_in[0];   // [8,2048,2048]
    const float* w1 = (const float*)d_in[1];   // [2048,256]
    const float* w2 = (const float*)d_in[2];   // [256,2048]
    const float* b1 = (const float*)d_in[3];   // [256]
    const float* b2 = (const float*)d_in[4];   // [2048]
    const float* s1 = (const float*)d_in[5];   // [1]
    const float* s2 = (const float*)d_in[6];   // [1]
    float* y = (float*)d_out;                  // [8,2048,2048] fp32

    constexpr int NROWS = 8 * 2048;  // 16384
    constexpr int D = 2048, R = 256;

    char* ws = (char*)d_ws;
    f16* W1t = (f16*)ws;                             // [R][D]  fp16, 1 MiB
    f16* W2t = (f16*)(ws + (size_t)R * D * 2);       // [D][R]  fp16, 1 MiB
    f16* H   = (f16*)(ws + (size_t)R * D * 4);       // [NROWS][R] fp16, 8 MiB

    // sparsify + transpose both weights (tiled, coalesced both sides)
    hipLaunchKernelGGL(sparsify_t_tiled, dim3(R / 64, D / 64), dim3(256),
                       0, stream, w1, s1, W1t, D, R);
    hipLaunchKernelGGL(sparsify_t_tiled, dim3(D / 64, R / 64), dim3(256),
                       0, stream, w2, s2, W2t, R, D);

    // GEMM1: grid 4 x 256 = 1024 blocks
    hipLaunchKernelGGL(gemm1_kernel, dim3(R / 64, NROWS / 64), dim3(256),
                       0, stream, x, W1t, b1, H);

    // GEMM2: grid 16 x 256 = 4096 blocks
    hipLaunchKernelGGL(gemm2_kernel, dim3(D / 128, NROWS / 64), dim3(256),
                       0, stream, H, W2t, b2, y);
}